// Round 1
// baseline (618.398 us; speedup 1.0000x reference)
//
#include <hip/hip_runtime.h>

// NormXCorr: B=16, D=64, H=48, W=24, p=5, d=2, n=25, EPS=0.01
// out[b, d*120 + a*24 + c, x, y] = mean_k En[b,d,x,y,k] * Fn[b,d,x+a,c,k]
// Algebra: sum_k En_k = 0 exactly, so ncc = (0.04*invX*invY) * sum_k (X_k-muX) * Y_k
//
// Restructure vs previous version: one 9-row x 5-col register window per thread
// slides over c computing ALL 5 vertical offsets a at once:
//   - Y columns read once per (x,c) instead of once per (x,a,c)  (5x fewer LDS reads)
//   - 5 independent 25-FMA accumulator chains per step (ILP)
//   - transposed LDS layouts (YpT, invYT) make per-step loads consecutive dwords
//   - odd strides 29/57/53 keep all access patterns bank-conflict-free

#define BH 48
#define BW 24
constexpr float EPS = 0.01f;

#define XPS 29   // Xp row stride     : Xp[row*29 + col],   row 0..51, col 0..27
#define YTS 57   // YpT column stride : YpT[col*57 + row],  col 0..27, row 0..55
#define IVS 53   // invYT stride      : invYT[col*53 + row],col 0..23, row 0..51

__global__ __launch_bounds__(192, 3) void ncc_kernel(const float* __restrict__ X,
                                                     const float* __restrict__ Y,
                                                     float* __restrict__ out) {
    __shared__ float Xp[52 * XPS];      // X padded +2 all sides (row-major)
    __shared__ float YpT[28 * YTS];     // Y padded +4 vert +2 horiz (TRANSPOSED)
    __shared__ float invYT[24 * IVS];   // 1/(sd+eps) per Y patch pos (TRANSPOSED)

    const int bd  = blockIdx.x;       // b*64 + d, 0..1023
    const int tid = threadIdx.x;      // 0..191

    const float* Xg = X + (size_t)bd * (BH * BW);
    const float* Yg = Y + (size_t)bd * (BH * BW);

    // ---- stage padded X slice (row-major, stride 29) ----
    for (int i = tid; i < 52 * 28; i += 192) {
        int r = i / 28, c = i % 28;
        int orr = r - 2, oc = c - 2;
        float v = 0.f;
        if (orr >= 0 && orr < BH && oc >= 0 && oc < BW) v = Xg[orr * BW + oc];
        Xp[r * XPS + c] = v;
    }
    // ---- stage padded Y slice transposed: YpT[col][row] ----
    // global read coalesced over c; LDS write stride 57 (odd) -> banks spread
    for (int i = tid; i < 56 * 28; i += 192) {
        int r = i / 28, c = i % 28;
        int orr = r - 4, oc = c - 2;
        float v = 0.f;
        if (orr >= 0 && orr < BH && oc >= 0 && oc < BW) v = Yg[orr * BW + oc];
        YpT[c * YTS + r] = v;
    }
    __syncthreads();

    // ---- Y patch inverse-std, stored transposed invYT[col][row] ----
    for (int i = tid; i < 52 * 24; i += 192) {
        int c = i % 24, r = i / 24;    // lanes: consecutive c -> stride 53/57, spread
        float s = 0.f, s2 = 0.f;
#pragma unroll
        for (int v = 0; v < 5; ++v)
#pragma unroll
            for (int u = 0; u < 5; ++u) {
                float val = YpT[(c + v) * YTS + (r + u)];
                s += val;
                s2 += val * val;
            }
        float mu  = s * 0.04f;
        float var = fmaxf(s2 * 0.04f - mu * mu, 0.f);
        invYT[c * IVS + r] = 1.f / (sqrtf(var) + EPS);
    }
    __syncthreads();

    // ---- main loop: thread = (x-octave, y); 6 x-iterations ----
    const int y  = tid % 24;   // X column
    const int xs = tid / 24;   // 0..7
    float* ob0 = out + (size_t)bd * (5 * 24 * 48 * 24);

#pragma unroll 1
    for (int xi = 0; xi < 6; ++xi) {
        const int x = xi * 8 + xs;  // 0..47

        // X patch -> registers, normalized, pre-scaled by 0.04*invX
        float xn[25];
        float s = 0.f, s2 = 0.f;
#pragma unroll
        for (int u = 0; u < 5; ++u)
#pragma unroll
            for (int v = 0; v < 5; ++v) {
                float val = Xp[(x + u) * XPS + (y + v)];
                xn[u * 5 + v] = val;
                s += val;
                s2 += val * val;
            }
        float mu  = s * 0.04f;
        float var = fmaxf(s2 * 0.04f - mu * mu, 0.f);
        float sc  = 0.04f / (sqrtf(var) + EPS);
#pragma unroll
        for (int k = 0; k < 25; ++k) xn[k] = (xn[k] - mu) * sc;

        float* ob = ob0 + x * 24 + y;   // lane-linear -> coalesced stores

        // 9-row x 5-col register window: rows x..x+8, ring over columns.
        // slot sl holds column c' with c' % 5 == sl. w[sl][r], r = row - x.
        float w[5][9];
#pragma unroll
        for (int v = 0; v < 5; ++v)
#pragma unroll
            for (int r = 0; r < 9; ++r)
                w[v][r] = YpT[v * YTS + x + r];   // consecutive dwords -> read2 merge

#pragma unroll
        for (int c = 0; c < 24; ++c) {
            float dot[5] = {0.f, 0.f, 0.f, 0.f, 0.f};
#pragma unroll
            for (int u = 0; u < 5; ++u)
#pragma unroll
                for (int v = 0; v < 5; ++v) {
                    const float f  = xn[u * 5 + v];
                    const int  sl  = (c + v) % 5;       // compile-time after unroll
#pragma unroll
                    for (int a = 0; a < 5; ++a)
                        dot[a] += f * w[sl][a + u];     // 5 independent chains
                }
#pragma unroll
            for (int a = 0; a < 5; ++a) {
                float iv = invYT[c * IVS + (x + a)];    // consecutive dwords
                ob[(size_t)(a * 24 + c) * (48 * 24)] = dot[a] * iv;
            }
            if (c < 23) {
                // load column c+5 into the slot just freed (slot c%5)
#pragma unroll
                for (int r = 0; r < 9; ++r)
                    w[c % 5][r] = YpT[(c + 5) * YTS + x + r];
            }
        }
    }
}

extern "C" void kernel_launch(void* const* d_in, const int* in_sizes, int n_in,
                              void* d_out, int out_size, void* d_ws, size_t ws_size,
                              hipStream_t stream) {
    const float* X = (const float*)d_in[0];
    const float* Y = (const float*)d_in[1];
    float* out = (float*)d_out;
    // d_in[2] is patch_size == 5, hardcoded above.
    ncc_kernel<<<dim3(1024), dim3(192), 0, stream>>>(X, Y, out);
}

// Round 2
// 589.727 us; speedup vs baseline: 1.0486x; 1.0486x over previous
//
#include <hip/hip_runtime.h>

// NormXCorr: B=16, D=64, H=48, W=24, p=5, d=2, n=25, EPS=0.01
// out[b, d*120 + a*24 + c, x, y] = mean_k En[b,d,x,y,k] * Fn[b,d,x+a,c,k]
// Algebra: sum_k En_k = 0 exactly, so ncc = (0.04*invX*invY) * sum_k (X_k-muX) * Y_k
//
// R2 change: occupancy. Grid 1024 -> 2048 (each block = one (b,d) slice x one
// x-half of 24 rows). Per-block staged footprint shrinks to 9.7 KB LDS;
// __launch_bounds__(192,5) caps VGPR ~102 -> ~6 blocks/CU resident
// (18 waves/CU vs previous grid-limited 12). Same FMA count, same stores.

#define BH 48
#define BW 24
constexpr float EPS = 0.01f;

#define XPS 29   // Xp row stride   : Xp[row*29 + col],    row 0..27, col 0..27
#define YTS 33   // YpT col stride  : YpT[col*33 + row],   col 0..27, row 0..31
#define IVS 29   // invYT stride    : invYT[col*29 + row], col 0..23, row 0..27

__global__ __launch_bounds__(192, 5) void ncc_kernel(const float* __restrict__ X,
                                                     const float* __restrict__ Y,
                                                     float* __restrict__ out) {
    __shared__ float Xp[28 * XPS];      // X rows [x0-2, x0+26), padded, row-major
    __shared__ float YpT[28 * YTS];     // Y rows [x0-4, x0+28), padded, TRANSPOSED
    __shared__ float invYT[24 * IVS];   // 1/(sd+eps), patch rows [x0, x0+28), transposed

    const int blk = blockIdx.x;        // 0..2047
    const int bd  = blk >> 1;          // (b*64+d), 0..1023
    const int xh  = blk & 1;           // x-half: rows [xh*24, xh*24+24)
    const int x0  = xh * 24;
    const int tid = threadIdx.x;       // 0..191

    const float* Xg = X + (size_t)bd * (BH * BW);
    const float* Yg = Y + (size_t)bd * (BH * BW);

    // ---- stage padded X rows [x0-2, x0+26) (row-major, stride 29) ----
    for (int i = tid; i < 28 * 28; i += 192) {
        int r = i / 28, c = i % 28;
        int g = x0 + r - 2, oc = c - 2;
        float v = 0.f;
        if (g >= 0 && g < BH && oc >= 0 && oc < BW) v = Xg[g * BW + oc];
        Xp[r * XPS + c] = v;
    }
    // ---- stage padded Y rows [x0-4, x0+28) transposed: YpT[col][row] ----
    for (int i = tid; i < 32 * 28; i += 192) {
        int r = i / 28, c = i % 28;
        int g = x0 + r - 4, oc = c - 2;
        float v = 0.f;
        if (g >= 0 && g < BH && oc >= 0 && oc < BW) v = Yg[g * BW + oc];
        YpT[c * YTS + r] = v;
    }
    __syncthreads();

    // ---- Y patch inverse-std for local patch rows 0..27, stored transposed ----
    for (int i = tid; i < 28 * 24; i += 192) {
        int c = i % 24, rl = i / 24;   // rl = local patch row (global row x0+rl)
        float s = 0.f, s2 = 0.f;
#pragma unroll
        for (int v = 0; v < 5; ++v)
#pragma unroll
            for (int u = 0; u < 5; ++u) {
                float val = YpT[(c + v) * YTS + (rl + u)];
                s += val;
                s2 += val * val;
            }
        float mu  = s * 0.04f;
        float var = fmaxf(s2 * 0.04f - mu * mu, 0.f);
        invYT[c * IVS + rl] = 1.f / (sqrtf(var) + EPS);
    }
    __syncthreads();

    // ---- main loop: thread = (x-octave, y); 3 x-iterations ----
    const int y  = tid % 24;   // X column
    const int xs = tid / 24;   // 0..7
    float* ob0 = out + (size_t)bd * (5 * 24 * 48 * 24);

#pragma unroll 1
    for (int xi = 0; xi < 3; ++xi) {
        const int lx = xi * 8 + xs;    // local x, 0..23
        const int x  = x0 + lx;        // global x

        // X patch -> registers, normalized, pre-scaled by 0.04*invX
        float xn[25];
        float s = 0.f, s2 = 0.f;
#pragma unroll
        for (int u = 0; u < 5; ++u)
#pragma unroll
            for (int v = 0; v < 5; ++v) {
                float val = Xp[(lx + u) * XPS + (y + v)];
                xn[u * 5 + v] = val;
                s += val;
                s2 += val * val;
            }
        float mu  = s * 0.04f;
        float var = fmaxf(s2 * 0.04f - mu * mu, 0.f);
        float sc  = 0.04f / (sqrtf(var) + EPS);
#pragma unroll
        for (int k = 0; k < 25; ++k) xn[k] = (xn[k] - mu) * sc;

        float* ob = ob0 + x * 24 + y;   // wave-store = contiguous 256 B

        // 9-row x 5-col register window over Y: rows lx..lx+8, ring over columns.
        // slot sl holds column c' with c' % 5 == sl. w[sl][r], r = row - lx.
        float w[5][9];
#pragma unroll
        for (int v = 0; v < 5; ++v)
#pragma unroll
            for (int r = 0; r < 9; ++r)
                w[v][r] = YpT[v * YTS + lx + r];

#pragma unroll
        for (int c = 0; c < 24; ++c) {
            float dot[5] = {0.f, 0.f, 0.f, 0.f, 0.f};
#pragma unroll
            for (int u = 0; u < 5; ++u)
#pragma unroll
                for (int v = 0; v < 5; ++v) {
                    const float f  = xn[u * 5 + v];
                    const int  sl  = (c + v) % 5;       // compile-time after unroll
#pragma unroll
                    for (int a = 0; a < 5; ++a)
                        dot[a] += f * w[sl][a + u];     // 5 independent chains
                }
#pragma unroll
            for (int a = 0; a < 5; ++a) {
                float iv = invYT[c * IVS + (lx + a)];
                ob[(size_t)(a * 24 + c) * (48 * 24)] = dot[a] * iv;
            }
            if (c < 23) {
                // load column c+5 into the slot just freed (slot c%5)
#pragma unroll
                for (int r = 0; r < 9; ++r)
                    w[c % 5][r] = YpT[(c + 5) * YTS + lx + r];
            }
        }
    }
}

extern "C" void kernel_launch(void* const* d_in, const int* in_sizes, int n_in,
                              void* d_out, int out_size, void* d_ws, size_t ws_size,
                              hipStream_t stream) {
    const float* X = (const float*)d_in[0];
    const float* Y = (const float*)d_in[1];
    float* out = (float*)d_out;
    // d_in[2] is patch_size == 5, hardcoded above.
    ncc_kernel<<<dim3(2048), dim3(192), 0, stream>>>(X, Y, out);
}